// Round 1
// baseline (432.912 us; speedup 1.0000x reference)
//
#include <hip/hip_runtime.h>

// Haar wavelet transform:
// in : (8, 32, 512, 512) fp32
// out: (8, 128, 256, 256) fp32  = concat([ll, lh, hl, hh], axis=1)
//
// One thread handles 2 output columns (one float4 load per input row,
// two input rows; one float2 store per band).

__global__ __launch_bounds__(256) void haar_kernel(const float* __restrict__ x,
                                                   float* __restrict__ out) {
    constexpr int C      = 32;
    constexpr int W      = 512;
    constexpr int OH     = 256;
    constexpr int OW     = 256;
    constexpr int OPLANE = OH * OW;       // 65536
    constexpr int JJ     = OW / 2;        // 128 column-pairs per output row

    int idx = blockIdx.x * blockDim.x + threadIdx.x;  // < 8*32*256*128 = 33,554,432

    int jj = idx & (JJ - 1);      // column-pair index (0..127)
    int t  = idx >> 7;
    int i  = t & (OH - 1);        // output row (0..255)
    int bc = t >> 8;              // fused batch*channel (0..255)
    int b  = bc >> 5;             // batch (0..7)
    int c  = bc & (C - 1);        // channel (0..31)

    // Input: rows 2i and 2i+1 of image bc, 4 consecutive floats at col 4*jj.
    const float4* inrow =
        reinterpret_cast<const float4*>(x + (size_t)bc * (W * W) + (size_t)(2 * i) * W);
    float4 top = inrow[jj];            // row 2i,   cols 4jj .. 4jj+3
    float4 bot = inrow[jj + (W / 4)];  // row 2i+1, cols 4jj .. 4jj+3

    // Pair 0: a=top.x b=top.y c=bot.x d=bot.y
    // Pair 1: a=top.z b=top.w c=bot.z d=bot.w
    float2 ll, lh, hl, hh;
    ll.x = 0.25f * (top.x + top.y + bot.x + bot.y);
    lh.x = 0.25f * (top.x - top.y + bot.x - bot.y);
    hl.x = 0.25f * (top.x + top.y - bot.x - bot.y);
    hh.x = 0.25f * (top.x - top.y - bot.x + bot.y);
    ll.y = 0.25f * (top.z + top.w + bot.z + bot.w);
    lh.y = 0.25f * (top.z - top.w + bot.z - bot.w);
    hl.y = 0.25f * (top.z + top.w - bot.z - bot.w);
    hh.y = 0.25f * (top.z - top.w - bot.z + bot.w);

    // Output (float2 units): band stride = C*OPLANE/2 float2s.
    constexpr size_t BAND2  = (size_t)C * OPLANE / 2;  // 1,048,576
    constexpr size_t BATCH2 = 4 * BAND2;               // per-batch stride in float2
    float2* o = reinterpret_cast<float2*>(out);
    size_t ob2 = (size_t)b * BATCH2 + (size_t)c * (OPLANE / 2) + (size_t)i * (OW / 2) + jj;

    o[ob2]             = ll;
    o[ob2 + BAND2]     = lh;
    o[ob2 + 2 * BAND2] = hl;
    o[ob2 + 3 * BAND2] = hh;
}

extern "C" void kernel_launch(void* const* d_in, const int* in_sizes, int n_in,
                              void* d_out, int out_size, void* d_ws, size_t ws_size,
                              hipStream_t stream) {
    const float* x = (const float*)d_in[0];
    float* out = (float*)d_out;

    const int total_threads = 8 * 32 * 256 * 128;  // 33,554,432
    const int block = 256;
    const int grid = total_threads / block;        // 131,072

    haar_kernel<<<grid, block, 0, stream>>>(x, out);
}